// Round 1
// baseline (129223.938 us; speedup 1.0000x reference)
//
#include <hip/hip_runtime.h>
#include <cmath>

#define SEQ 4096
#define INP 457
#define EMB 2048
#define NWG_E 256   // encoder: 1 WG per CU, weights resident in VGPRs
#define NWG_D 29    // decoder: 29 WGs x 16 c-indices = 464 >= 457

typedef unsigned long long u64t;

__device__ __forceinline__ float sigf(float v) { return 1.0f / (1.0f + expf(-v)); }

// ---------------- bias precompute: bsum = enc_bih+enc_bhh, btot = dec_bih+dec_bhh ----------------
__global__ void bias_kernel(const float* __restrict__ ebih, const float* __restrict__ ebhh,
                            const float* __restrict__ dbih, const float* __restrict__ dbhh,
                            float* __restrict__ bsum, float* __restrict__ btot) {
  int i = blockIdx.x * 256 + threadIdx.x;
  if (i < 4 * EMB) bsum[i] = ebih[i] + ebhh[i];
  if (i < 4 * INP) btot[i] = dbih[i] + dbhh[i];
}

// ---------------- Wfold = (dec_Wih + dec_Whh) @ dec_Whr  -> (1828 x 480 padded, pad cols = 0) ----
__global__ __launch_bounds__(256) void fold_gemm(const float* __restrict__ dWih,
                                                 const float* __restrict__ dWhh,
                                                 const float* __restrict__ dWhr,
                                                 float* __restrict__ C) {
  const int bx = blockIdx.x;        // col tiles: 8 x 64 (covers padded 480.. guarded at 480)
  const int by = blockIdx.y;        // row tiles: 29 x 64 (1856 >= 1828)
  const int tid = threadIdx.x;
  const int tx = tid & 15, ty = tid >> 4;
  __shared__ float As[16][65];
  __shared__ float Bs[16][65];
  float acc[4][4] = {};
  for (int k0 = 0; k0 < EMB; k0 += 16) {
#pragma unroll
    for (int e = 0; e < 4; ++e) {
      int eid = tid * 4 + e;              // 0..1023
      int m = eid >> 4, k = eid & 15;
      int row = by * 64 + m;
      float v = 0.0f;
      if (row < 4 * INP) {
        size_t a = (size_t)row * EMB + k0 + k;
        v = dWih[a] + dWhh[a];
      }
      As[k][m] = v;
    }
#pragma unroll
    for (int e = 0; e < 4; ++e) {
      int eid = tid * 4 + e;
      int k = eid >> 6, c = eid & 63;
      int col = bx * 64 + c;
      Bs[k][c] = (col < INP) ? dWhr[(size_t)(k0 + k) * INP + col] : 0.0f;
    }
    __syncthreads();
#pragma unroll
    for (int k = 0; k < 16; ++k) {
      float a0 = As[k][ty * 4 + 0], a1 = As[k][ty * 4 + 1], a2 = As[k][ty * 4 + 2], a3 = As[k][ty * 4 + 3];
      float b0 = Bs[k][tx * 4 + 0], b1 = Bs[k][tx * 4 + 1], b2 = Bs[k][tx * 4 + 2], b3 = Bs[k][tx * 4 + 3];
      acc[0][0] += a0 * b0; acc[0][1] += a0 * b1; acc[0][2] += a0 * b2; acc[0][3] += a0 * b3;
      acc[1][0] += a1 * b0; acc[1][1] += a1 * b1; acc[1][2] += a1 * b2; acc[1][3] += a1 * b3;
      acc[2][0] += a2 * b0; acc[2][1] += a2 * b1; acc[2][2] += a2 * b2; acc[2][3] += a2 * b3;
      acc[3][0] += a3 * b0; acc[3][1] += a3 * b1; acc[3][2] += a3 * b2; acc[3][3] += a3 * b3;
    }
    __syncthreads();
  }
#pragma unroll
  for (int i = 0; i < 4; ++i) {
    int row = by * 64 + ty * 4 + i;
    if (row >= 4 * INP) continue;
#pragma unroll
    for (int j = 0; j < 4; ++j) {
      int col = bx * 64 + tx * 4 + j;
      if (col < 480) C[(size_t)row * 480 + col] = acc[i][j];
    }
  }
}

// ---------------- persistent encoder ----------------
// 256 WGs x 256 thr. WG w owns h-indices [w*8, w*8+8) -> 32 gate rows (4 gates x 8).
// thread (r = tid&31 row, kc = tid>>5 of 8 k-chunks): holds Whh[row][kc*256..+256) (256 VGPRs)
// + Wih[row][kc*60..+60) (60 VGPRs, zero-padded past 457). h broadcast via LLC atomics.
__global__ __launch_bounds__(256, 1) void enc_kernel(
    const float* __restrict__ x, const float* __restrict__ Wih,
    const float* __restrict__ Whh, const float* __restrict__ bsum,
    float* __restrict__ hbuf, unsigned* __restrict__ cnt) {
  const int tid = threadIdx.x;
  const int wg  = blockIdx.x;
  const int r   = tid & 31;
  const int kc  = tid >> 5;
  const int jbase = wg * 8;
  const int grow = (r >> 3) * EMB + jbase + (r & 7);

  float wh[256];
#pragma unroll
  for (int i4 = 0; i4 < 64; ++i4) {
    const float4 v = *(const float4*)(Whh + (size_t)grow * EMB + kc * 256 + i4 * 4);
    wh[i4 * 4 + 0] = v.x; wh[i4 * 4 + 1] = v.y; wh[i4 * 4 + 2] = v.z; wh[i4 * 4 + 3] = v.w;
  }
  float wx[60];
#pragma unroll
  for (int i = 0; i < 60; ++i) {
    const int k = kc * 60 + i;
    wx[i] = (k < INP) ? Wih[(size_t)grow * INP + k] : 0.0f;
  }

  __shared__ float part[8][33];
  __shared__ float gates[32];
  __shared__ float c_s[8];
  float bias = 0.0f;
  if (tid < 32) bias = bsum[(tid >> 3) * EMB + jbase + (tid & 7)];
  if (tid < 8)  c_s[tid] = 0.0f;
  __syncthreads();

  const u64t* __restrict__ hb = (const u64t*)hbuf;

  for (int t = 0; t < SEQ; ++t) {
    const float* __restrict__ xrow = x + (size_t)t * INP;
    const u64t* hsrc = hb + (size_t)(t & 1) * (EMB / 2) + kc * 128;
    float a0 = 0.f, a1 = 0.f, a2 = 0.f, a3 = 0.f;
#pragma unroll
    for (int i = 0; i < 128; ++i) {
      u64t u = __hip_atomic_load((u64t*)(hsrc + i), __ATOMIC_RELAXED, __HIP_MEMORY_SCOPE_AGENT);
      float2 f = __builtin_bit_cast(float2, u);
      if ((i & 1) == 0) { a0 += wh[2 * i] * f.x; a1 += wh[2 * i + 1] * f.y; }
      else              { a2 += wh[2 * i] * f.x; a3 += wh[2 * i + 1] * f.y; }
    }
#pragma unroll
    for (int i = 0; i < 60; ++i) {
      const int k = kc * 60 + i;
      const int kcl = (k < INP) ? k : (INP - 1);  // wx is 0 past 457, clamp keeps address legal
      const float xv = xrow[kcl];
      if ((i & 1) == 0) a0 += wx[i] * xv; else a1 += wx[i] * xv;
    }
    part[kc][r] = (a0 + a1) + (a2 + a3);
    __syncthreads();
    if (tid < 32) {
      gates[tid] = part[0][tid] + part[1][tid] + part[2][tid] + part[3][tid]
                 + part[4][tid] + part[5][tid] + part[6][tid] + part[7][tid] + bias;
    }
    __syncthreads();
    if (tid < 8) {
      const float gi = gates[tid], gf = gates[8 + tid], gg = gates[16 + tid], go = gates[24 + tid];
      const float cN = sigf(gf) * c_s[tid] + sigf(gi) * tanhf(gg);
      c_s[tid] = cN;
      const float hN = sigf(go) * tanhf(cN);
      __hip_atomic_store(hbuf + (size_t)((t + 1) & 1) * EMB + jbase + tid, hN,
                         __ATOMIC_RELAXED, __HIP_MEMORY_SCOPE_AGENT);
    }
    if (t < SEQ - 1) {
      __syncthreads();
      if (tid == 0) {
        __threadfence();
        __hip_atomic_fetch_add(cnt, 1u, __ATOMIC_RELAXED, __HIP_MEMORY_SCOPE_AGENT);
        const unsigned target = (unsigned)NWG_E * (unsigned)(t + 1);
        while (__hip_atomic_load(cnt, __ATOMIC_RELAXED, __HIP_MEMORY_SCOPE_AGENT) < target)
          __builtin_amdgcn_s_sleep(1);
        __threadfence();
      }
      __syncthreads();
    }
  }
}

// ---------------- persistent decoder ----------------
// 29 WGs x 256 thr. WG w owns c-indices [w*16, w*16+16) -> 64 gate rows. thread (r=tid&63, kc=tid>>6):
// holds Wfold[row][kc*120..+120) (120 VGPRs). Step 0 streams dec_Wih @ h_enc from global.
__global__ __launch_bounds__(256, 1) void dec_kernel(
    const float* __restrict__ dWih, const float* __restrict__ Wfold,
    const float* __restrict__ btot, const float* __restrict__ henc,
    float* __restrict__ hraw, float* __restrict__ out, unsigned* __restrict__ cnt) {
  const int tid = threadIdx.x;
  const int wg  = blockIdx.x;
  const int r   = tid & 63;
  const int kc  = tid >> 6;
  const int g   = r >> 4;
  const int jj  = r & 15;
  const int idx = wg * 16 + jj;
  const bool valid = (idx < INP);
  const int grow = g * INP + (valid ? idx : 0);

  float wd[120];
#pragma unroll
  for (int i4 = 0; i4 < 30; ++i4) {
    float4 v = make_float4(0.f, 0.f, 0.f, 0.f);
    if (valid) v = *(const float4*)(Wfold + (size_t)grow * 480 + kc * 120 + i4 * 4);
    wd[i4 * 4 + 0] = v.x; wd[i4 * 4 + 1] = v.y; wd[i4 * 4 + 2] = v.z; wd[i4 * 4 + 3] = v.w;
  }

  __shared__ float part[4][65];
  __shared__ float gates[64];
  __shared__ float c_s[16];
  float bias = 0.0f;
  if (tid < 64) {
    const int g2 = tid >> 4, j2 = tid & 15, ix2 = wg * 16 + j2;
    if (ix2 < INP) bias = btot[g2 * INP + ix2];
  }
  if (tid < 16) c_s[tid] = 0.0f;
  __syncthreads();

  for (int t = 0; t < SEQ; ++t) {
    float a0 = 0.f, a1 = 0.f, a2 = 0.f, a3 = 0.f;
    if (t == 0) {
      if (valid) {
#pragma unroll 8
        for (int i4 = 0; i4 < 128; ++i4) {
          const float4 w  = *(const float4*)(dWih + (size_t)grow * EMB + kc * 512 + i4 * 4);
          const float4 hv = *(const float4*)(henc + kc * 512 + i4 * 4);
          a0 += w.x * hv.x; a1 += w.y * hv.y; a2 += w.z * hv.z; a3 += w.w * hv.w;
        }
      }
    } else {
      const u64t* hs = (const u64t*)(hraw + (size_t)(t & 1) * 512) + kc * 60;
#pragma unroll
      for (int i = 0; i < 60; ++i) {
        u64t u = __hip_atomic_load((u64t*)(hs + i), __ATOMIC_RELAXED, __HIP_MEMORY_SCOPE_AGENT);
        float2 f = __builtin_bit_cast(float2, u);
        if ((i & 1) == 0) { a0 += wd[2 * i] * f.x; a1 += wd[2 * i + 1] * f.y; }
        else              { a2 += wd[2 * i] * f.x; a3 += wd[2 * i + 1] * f.y; }
      }
    }
    part[kc][r] = (a0 + a1) + (a2 + a3);
    __syncthreads();
    if (tid < 64) gates[tid] = part[0][tid] + part[1][tid] + part[2][tid] + part[3][tid] + bias;
    __syncthreads();
    if (tid < 16 && (wg * 16 + tid) < INP) {
      const int ix = wg * 16 + tid;
      const float gi = gates[tid], gf = gates[16 + tid], gg = gates[32 + tid], go = gates[48 + tid];
      const float cN = sigf(gf) * c_s[tid] + sigf(gi) * tanhf(gg);
      c_s[tid] = cN;
      out[(size_t)(SEQ - 1 - t) * INP + ix] = cN;   // reversed row order; softmax'd later
      const float hrN = sigf(go) * tanhf(cN);
      __hip_atomic_store(hraw + (size_t)((t + 1) & 1) * 512 + ix, hrN,
                         __ATOMIC_RELAXED, __HIP_MEMORY_SCOPE_AGENT);
    }
    if (t < SEQ - 1) {
      __syncthreads();
      if (tid == 0) {
        __threadfence();
        __hip_atomic_fetch_add(cnt, 1u, __ATOMIC_RELAXED, __HIP_MEMORY_SCOPE_AGENT);
        const unsigned target = (unsigned)NWG_D * (unsigned)(t + 1);
        while (__hip_atomic_load(cnt, __ATOMIC_RELAXED, __HIP_MEMORY_SCOPE_AGENT) < target)
          __builtin_amdgcn_s_sleep(1);
        __threadfence();
      }
      __syncthreads();
    }
  }
}

// ---------------- row softmax in-place on d_out (4096 x 457) ----------------
__global__ __launch_bounds__(512) void softmax_kernel(float* __restrict__ out) {
  const int row = blockIdx.x;
  const int tid = threadIdx.x;
  __shared__ float red[512];
  float* rp = out + (size_t)row * INP;
  float v = (tid < INP) ? rp[tid] : -INFINITY;
  red[tid] = v;
  __syncthreads();
#pragma unroll
  for (int off = 256; off > 0; off >>= 1) {
    if (tid < off) red[tid] = fmaxf(red[tid], red[tid + off]);
    __syncthreads();
  }
  const float m = red[0];
  __syncthreads();
  const float e = (tid < INP) ? expf(v - m) : 0.0f;
  red[tid] = e;
  __syncthreads();
#pragma unroll
  for (int off = 256; off > 0; off >>= 1) {
    if (tid < off) red[tid] = red[tid] + red[tid + off];
    __syncthreads();
  }
  const float s = red[0];
  if (tid < INP) rp[tid] = e / s;
}

extern "C" void kernel_launch(void* const* d_in, const int* in_sizes, int n_in,
                              void* d_out, int out_size, void* d_ws, size_t ws_size,
                              hipStream_t stream) {
  const float* x    = (const float*)d_in[0];
  const float* eWih = (const float*)d_in[1];
  const float* eWhh = (const float*)d_in[2];
  const float* ebih = (const float*)d_in[3];
  const float* ebhh = (const float*)d_in[4];
  const float* dWih = (const float*)d_in[5];
  const float* dWhh = (const float*)d_in[6];
  const float* dbih = (const float*)d_in[7];
  const float* dbhh = (const float*)d_in[8];
  const float* dWhr = (const float*)d_in[9];
  float* out = (float*)d_out;
  char* ws = (char*)d_ws;

  // ws layout (ws re-poisoned each launch -> re-init here):
  // [0,64):      encoder barrier counter   [64,128): decoder barrier counter
  // [4096):      hbuf 2x2048 f32 (double-buffered h; buf0 = h0 = 0)
  // [20480):     hraw 2x512 f32 (double-buffered decoder hraw, zero pad)
  // [24576):     bsum 8192 f32
  // [57344):     btot 1828 f32 (pad to 2048)
  // [65536):     Wfold 1828x480 f32 (~3.5 MB)  -> total ~3.6 MB
  unsigned* cnt_e = (unsigned*)(ws + 0);
  unsigned* cnt_d = (unsigned*)(ws + 64);
  float* hbuf  = (float*)(ws + 4096);
  float* hraw  = (float*)(ws + 4096 + 16384);
  float* bsum  = (float*)(ws + 24576);
  float* btot  = (float*)(ws + 24576 + 32768);
  float* Wfold = (float*)(ws + 65536);

  hipMemsetAsync(ws, 0, 24576, stream);  // counters + hbuf + hraw
  bias_kernel<<<40, 256, 0, stream>>>(ebih, ebhh, dbih, dbhh, bsum, btot);
  fold_gemm<<<dim3(8, 29), 256, 0, stream>>>(dWih, dWhh, dWhr, Wfold);
  enc_kernel<<<NWG_E, 256, 0, stream>>>(x, eWih, eWhh, bsum, hbuf, cnt_e);
  dec_kernel<<<NWG_D, 256, 0, stream>>>(dWih, Wfold, btot, hbuf, hraw, out, cnt_d);
  softmax_kernel<<<SEQ, 512, 0, stream>>>(out);
}

// Round 2
// 77295.197 us; speedup vs baseline: 1.6718x; 1.6718x over previous
//
#include <hip/hip_runtime.h>
#include <cmath>

#define SEQ 4096
#define INP 457
#define EMB 2048
#define NWG_E 256   // encoder: 1 WG per CU, Whh+Wih register-resident
#define NWG_D 29    // decoder: 29 WGs x 16 c-indices = 464 >= 457

typedef unsigned long long u64t;

__device__ __forceinline__ float sigf(float v) { return 1.0f / (1.0f + expf(-v)); }

// ---------------- bias precompute ----------------
__global__ void bias_kernel(const float* __restrict__ ebih, const float* __restrict__ ebhh,
                            const float* __restrict__ dbih, const float* __restrict__ dbhh,
                            float* __restrict__ bsum, float* __restrict__ btot) {
  int i = blockIdx.x * 256 + threadIdx.x;
  if (i < 4 * EMB) bsum[i] = ebih[i] + ebhh[i];
  if (i < 4 * INP) btot[i] = dbih[i] + dbhh[i];
}

// ---------------- Wfold = (dec_Wih + dec_Whh) @ dec_Whr  (1828 x 480, pad cols zero) ----------------
__global__ __launch_bounds__(256) void fold_gemm(const float* __restrict__ dWih,
                                                 const float* __restrict__ dWhh,
                                                 const float* __restrict__ dWhr,
                                                 float* __restrict__ C) {
  const int bx = blockIdx.x, by = blockIdx.y;
  const int tid = threadIdx.x;
  const int tx = tid & 15, ty = tid >> 4;
  __shared__ float As[16][65];
  __shared__ float Bs[16][65];
  float acc[4][4] = {};
  for (int k0 = 0; k0 < EMB; k0 += 16) {
#pragma unroll
    for (int e = 0; e < 4; ++e) {
      int eid = tid * 4 + e;
      int m = eid >> 4, k = eid & 15;
      int row = by * 64 + m;
      float v = 0.0f;
      if (row < 4 * INP) {
        size_t a = (size_t)row * EMB + k0 + k;
        v = dWih[a] + dWhh[a];
      }
      As[k][m] = v;
    }
#pragma unroll
    for (int e = 0; e < 4; ++e) {
      int eid = tid * 4 + e;
      int k = eid >> 6, c = eid & 63;
      int col = bx * 64 + c;
      Bs[k][c] = (col < INP) ? dWhr[(size_t)(k0 + k) * INP + col] : 0.0f;
    }
    __syncthreads();
#pragma unroll
    for (int k = 0; k < 16; ++k) {
      float a0 = As[k][ty * 4 + 0], a1 = As[k][ty * 4 + 1], a2 = As[k][ty * 4 + 2], a3 = As[k][ty * 4 + 3];
      float b0 = Bs[k][tx * 4 + 0], b1 = Bs[k][tx * 4 + 1], b2 = Bs[k][tx * 4 + 2], b3 = Bs[k][tx * 4 + 3];
      acc[0][0] += a0 * b0; acc[0][1] += a0 * b1; acc[0][2] += a0 * b2; acc[0][3] += a0 * b3;
      acc[1][0] += a1 * b0; acc[1][1] += a1 * b1; acc[1][2] += a1 * b2; acc[1][3] += a1 * b3;
      acc[2][0] += a2 * b0; acc[2][1] += a2 * b1; acc[2][2] += a2 * b2; acc[2][3] += a2 * b3;
      acc[3][0] += a3 * b0; acc[3][1] += a3 * b1; acc[3][2] += a3 * b2; acc[3][3] += a3 * b3;
    }
    __syncthreads();
  }
#pragma unroll
  for (int i = 0; i < 4; ++i) {
    int row = by * 64 + ty * 4 + i;
    if (row >= 4 * INP) continue;
#pragma unroll
    for (int j = 0; j < 4; ++j) {
      int col = bx * 64 + tx * 4 + j;
      if (col < 480) C[(size_t)row * 480 + col] = acc[i][j];
    }
  }
}

// ---------------- persistent encoder ----------------
// WG w owns h-indices [w*8, w*8+8). Thread: j = tid&7 (h-idx), kc = tid>>3 (32 k-chunks of 64).
// Registers: Whh 4 gate rows x 64 k = 64 float4; Wih 4 rows x 16 k = 16 float4 (zero-padded).
// h staged to LDS per step via agent-atomic u64 loads; XOR-swizzled 16B granules -> conflict-free b128 reads.
// Barrier: 8 arrival lines + sum-poll with s_sleep(2).
__global__ __launch_bounds__(256, 1) void enc_kernel(
    const float* __restrict__ x, const float* __restrict__ Wih,
    const float* __restrict__ Whh, const float* __restrict__ bsum,
    float* __restrict__ hbuf, unsigned* __restrict__ arr) {
  const int tid = threadIdx.x;
  const int wg  = blockIdx.x;
  const int j   = tid & 7;
  const int kc  = tid >> 3;          // 0..31
  const int jbase = wg * 8;

  float4 whh4[4][16];
  float4 wih4[4][4];
#pragma unroll
  for (int g = 0; g < 4; ++g) {
    const size_t row = (size_t)(g * EMB + jbase + j);
    const float* wp = Whh + row * EMB + kc * 64;
#pragma unroll
    for (int q = 0; q < 16; ++q) whh4[g][q] = *(const float4*)(wp + 4 * q);
    const float* ip = Wih + row * INP;
#pragma unroll
    for (int q = 0; q < 4; ++q) {
      const int c0 = kc * 16 + q * 4;
      float4 v;
      v.x = (c0 + 0 < INP) ? ip[c0 + 0] : 0.0f;
      v.y = (c0 + 1 < INP) ? ip[c0 + 1] : 0.0f;
      v.z = (c0 + 2 < INP) ? ip[c0 + 2] : 0.0f;
      v.w = (c0 + 3 < INP) ? ip[c0 + 3] : 0.0f;
      wih4[g][q] = v;
    }
  }

  __shared__ float4 hlds4[512];        // 8 KB, swizzled granules of h
  __shared__ float4 xlds4[2][128];     // double-buffered x row (512 floats each)
  __shared__ float  partbuf[128];      // [wave][j][gate]
  __shared__ float  gl[32];
  __shared__ float  c_s[8];

  float bias = 0.0f;
  if (tid < 32) bias = bsum[(tid >> 3) * EMB + jbase + (tid & 7)];
  if (tid < 8)  c_s[tid] = 0.0f;

  { // prefetch x[0]
    const int i0 = tid * 2, i1 = tid * 2 + 1;
    float* xw = (float*)xlds4[0];
    xw[i0] = (i0 < INP) ? x[i0] : 0.0f;
    xw[i1] = (i1 < INP) ? x[i1] : 0.0f;
  }

  // swizzled granule indices (constant over steps)
  const int s = kc & 15;
  int hidx[16];
#pragma unroll
  for (int q = 0; q < 16; ++q) hidx[q] = kc * 16 + (q ^ s);
  const int g0 = 2 * tid, g1 = 2 * tid + 1;
  const int wphys0 = g0 ^ ((g0 >> 4) & 15);
  const int wphys1 = g1 ^ ((g1 >> 4) & 15);
  __syncthreads();

  for (int t = 0; t < SEQ; ++t) {
    // ---- stage h_t into LDS (agent-atomic, L1-safe) ----
    const u64t* hsg = (const u64t*)(hbuf + (size_t)(t & 1) * EMB) + tid * 4;
    const u64t u0 = __hip_atomic_load((u64t*)(hsg + 0), __ATOMIC_RELAXED, __HIP_MEMORY_SCOPE_AGENT);
    const u64t u1 = __hip_atomic_load((u64t*)(hsg + 1), __ATOMIC_RELAXED, __HIP_MEMORY_SCOPE_AGENT);
    const u64t u2 = __hip_atomic_load((u64t*)(hsg + 2), __ATOMIC_RELAXED, __HIP_MEMORY_SCOPE_AGENT);
    const u64t u3 = __hip_atomic_load((u64t*)(hsg + 3), __ATOMIC_RELAXED, __HIP_MEMORY_SCOPE_AGENT);
    const float2 f0 = __builtin_bit_cast(float2, u0);
    const float2 f1 = __builtin_bit_cast(float2, u1);
    const float2 f2 = __builtin_bit_cast(float2, u2);
    const float2 f3 = __builtin_bit_cast(float2, u3);
    hlds4[wphys0] = make_float4(f0.x, f0.y, f1.x, f1.y);
    hlds4[wphys1] = make_float4(f2.x, f2.y, f3.x, f3.y);
    __syncthreads();

    float4 a0 = make_float4(0, 0, 0, 0), a1 = a0, a2 = a0, a3 = a0;
    // x part (from LDS, prefetched last step)
    const float4* xb = xlds4[t & 1];
#pragma unroll
    for (int q = 0; q < 4; ++q) {
      const float4 hv = xb[kc * 4 + q];
      a0.x += wih4[0][q].x * hv.x; a0.y += wih4[0][q].y * hv.y; a0.z += wih4[0][q].z * hv.z; a0.w += wih4[0][q].w * hv.w;
      a1.x += wih4[1][q].x * hv.x; a1.y += wih4[1][q].y * hv.y; a1.z += wih4[1][q].z * hv.z; a1.w += wih4[1][q].w * hv.w;
      a2.x += wih4[2][q].x * hv.x; a2.y += wih4[2][q].y * hv.y; a2.z += wih4[2][q].z * hv.z; a2.w += wih4[2][q].w * hv.w;
      a3.x += wih4[3][q].x * hv.x; a3.y += wih4[3][q].y * hv.y; a3.z += wih4[3][q].z * hv.z; a3.w += wih4[3][q].w * hv.w;
    }
    // h part (swizzled conflict-free b128 reads)
#pragma unroll
    for (int q = 0; q < 16; ++q) {
      const float4 hv = hlds4[hidx[q]];
      a0.x += whh4[0][q].x * hv.x; a0.y += whh4[0][q].y * hv.y; a0.z += whh4[0][q].z * hv.z; a0.w += whh4[0][q].w * hv.w;
      a1.x += whh4[1][q].x * hv.x; a1.y += whh4[1][q].y * hv.y; a1.z += whh4[1][q].z * hv.z; a1.w += whh4[1][q].w * hv.w;
      a2.x += whh4[2][q].x * hv.x; a2.y += whh4[2][q].y * hv.y; a2.z += whh4[2][q].z * hv.z; a2.w += whh4[2][q].w * hv.w;
      a3.x += whh4[3][q].x * hv.x; a3.y += whh4[3][q].y * hv.y; a3.z += whh4[3][q].z * hv.z; a3.w += whh4[3][q].w * hv.w;
    }

    // issue x[t+1] prefetch loads (latency hidden under reduction)
    const int nt = t + 1;
    float pv0 = 0.0f, pv1 = 0.0f;
    if (nt < SEQ) {
      const float* xr = x + (size_t)nt * INP;
      const int i0 = tid * 2, i1 = i0 + 1;
      if (i0 < INP) pv0 = xr[i0];
      if (i1 < INP) pv1 = xr[i1];
    }

    // reduce: horizontal + in-wave butterfly over kc bits (lane bits 3,4,5)
    float r0 = (a0.x + a0.y) + (a0.z + a0.w);
    float r1 = (a1.x + a1.y) + (a1.z + a1.w);
    float r2 = (a2.x + a2.y) + (a2.z + a2.w);
    float r3 = (a3.x + a3.y) + (a3.z + a3.w);
#pragma unroll
    for (int m = 8; m < 64; m <<= 1) {
      r0 += __shfl_xor(r0, m);
      r1 += __shfl_xor(r1, m);
      r2 += __shfl_xor(r2, m);
      r3 += __shfl_xor(r3, m);
    }
    if ((tid & 63) < 8) {
      const int w = tid >> 6;
      const int base = (w * 8 + (tid & 7)) * 4;
      partbuf[base + 0] = r0; partbuf[base + 1] = r1;
      partbuf[base + 2] = r2; partbuf[base + 3] = r3;
    }
    __syncthreads();
    if (tid < 32) {
      const int jj = tid & 7, g = tid >> 3;
      float v = bias;
#pragma unroll
      for (int w = 0; w < 4; ++w) v += partbuf[(w * 8 + jj) * 4 + g];
      gl[g * 8 + jj] = v;
    }
    __syncthreads();
    if (tid < 8) {
      const float gi = gl[tid], gf = gl[8 + tid], gg = gl[16 + tid], go = gl[24 + tid];
      const float cN = sigf(gf) * c_s[tid] + sigf(gi) * tanhf(gg);
      c_s[tid] = cN;
      const float hN = sigf(go) * tanhf(cN);
      __hip_atomic_store(hbuf + (size_t)((t + 1) & 1) * EMB + jbase + tid, hN,
                         __ATOMIC_RELAXED, __HIP_MEMORY_SCOPE_AGENT);
    }
    if (nt < SEQ) {  // commit x prefetch to the other LDS buffer
      float* xw = (float*)xlds4[nt & 1];
      xw[tid * 2] = pv0; xw[tid * 2 + 1] = pv1;
    }
    if (t < SEQ - 1) {
      __syncthreads();
      if (tid == 0) {
        __threadfence();
        __hip_atomic_fetch_add(&arr[(wg & 7) * 32], 1u, __ATOMIC_RELAXED, __HIP_MEMORY_SCOPE_AGENT);
        const unsigned target = (unsigned)NWG_E * (unsigned)(t + 1);
        for (;;) {
          unsigned sum = 0;
#pragma unroll
          for (int i = 0; i < 8; ++i)
            sum += __hip_atomic_load(&arr[i * 32], __ATOMIC_RELAXED, __HIP_MEMORY_SCOPE_AGENT);
          if (sum >= target) break;
          __builtin_amdgcn_s_sleep(2);
        }
        __threadfence();
      }
      __syncthreads();
    }
  }
}

// ---------------- persistent decoder ----------------
// WG w owns c-indices [w*16, w*16+16). Thread: jj = tid&15 (c-idx), kc = tid>>4 (16 k-chunks of 30).
// Registers: Wfold 4 gate rows x 30 k = 60 float2. hraw staged via LDS.
__global__ __launch_bounds__(256, 1) void dec_kernel(
    const float* __restrict__ dWih, const float* __restrict__ Wfold,
    const float* __restrict__ btot, const float* __restrict__ henc,
    float* __restrict__ hraw, float* __restrict__ out, unsigned* __restrict__ cnt) {
  const int tid = threadIdx.x;
  const int wg  = blockIdx.x;
  const int jj  = tid & 15;
  const int kc  = tid >> 4;          // 0..15
  const int idx = wg * 16 + jj;
  const bool valid = (idx < INP);
  const int id0 = valid ? idx : 0;

  float2 wd2[4][15];
#pragma unroll
  for (int g = 0; g < 4; ++g) {
    const float* wp = Wfold + (size_t)(g * INP + id0) * 480 + kc * 30;
#pragma unroll
    for (int q = 0; q < 15; ++q)
      wd2[g][q] = valid ? *(const float2*)(wp + 2 * q) : make_float2(0.0f, 0.0f);
  }

  __shared__ float2 dl2[256];      // staged hraw (480 floats used; pad zeros)
  __shared__ float  partbuf[256];  // [wave][jj][gate]
  __shared__ float  gl[64];
  __shared__ float  c_s[16];
  float bias = 0.0f;
  if (tid < 64) {
    const int g2 = tid >> 4, j2 = tid & 15, ix = wg * 16 + j2;
    if (ix < INP) bias = btot[g2 * INP + ix];
  }
  if (tid < 16) c_s[tid] = 0.0f;
  __syncthreads();

  for (int t = 0; t < SEQ; ++t) {
    float2 acc0 = make_float2(0, 0), acc1 = acc0, acc2 = acc0, acc3 = acc0;
    if (t == 0) {
      if (valid) {
#pragma unroll 4
        for (int q = 0; q < 32; ++q) {
          const float4 hv = *(const float4*)(henc + kc * 128 + 4 * q);
          const float4 w0 = *(const float4*)(dWih + (size_t)(0 * INP + idx) * EMB + kc * 128 + 4 * q);
          const float4 w1 = *(const float4*)(dWih + (size_t)(1 * INP + idx) * EMB + kc * 128 + 4 * q);
          const float4 w2 = *(const float4*)(dWih + (size_t)(2 * INP + idx) * EMB + kc * 128 + 4 * q);
          const float4 w3 = *(const float4*)(dWih + (size_t)(3 * INP + idx) * EMB + kc * 128 + 4 * q);
          acc0.x += w0.x * hv.x + w0.z * hv.z; acc0.y += w0.y * hv.y + w0.w * hv.w;
          acc1.x += w1.x * hv.x + w1.z * hv.z; acc1.y += w1.y * hv.y + w1.w * hv.w;
          acc2.x += w2.x * hv.x + w2.z * hv.z; acc2.y += w2.y * hv.y + w2.w * hv.w;
          acc3.x += w3.x * hv.x + w3.z * hv.z; acc3.y += w3.y * hv.y + w3.w * hv.w;
        }
      }
    } else {
      if (tid < 240) {
        const u64t u = __hip_atomic_load((u64t*)((const u64t*)(hraw + (size_t)(t & 1) * 512) + tid),
                                         __ATOMIC_RELAXED, __HIP_MEMORY_SCOPE_AGENT);
        dl2[tid] = __builtin_bit_cast(float2, u);
      }
      __syncthreads();
#pragma unroll
      for (int q = 0; q < 15; ++q) {
        const float2 hv = dl2[kc * 15 + q];
        acc0.x += wd2[0][q].x * hv.x; acc0.y += wd2[0][q].y * hv.y;
        acc1.x += wd2[1][q].x * hv.x; acc1.y += wd2[1][q].y * hv.y;
        acc2.x += wd2[2][q].x * hv.x; acc2.y += wd2[2][q].y * hv.y;
        acc3.x += wd2[3][q].x * hv.x; acc3.y += wd2[3][q].y * hv.y;
      }
    }
    float r0 = acc0.x + acc0.y, r1 = acc1.x + acc1.y, r2 = acc2.x + acc2.y, r3 = acc3.x + acc3.y;
#pragma unroll
    for (int m = 16; m < 64; m <<= 1) {
      r0 += __shfl_xor(r0, m);
      r1 += __shfl_xor(r1, m);
      r2 += __shfl_xor(r2, m);
      r3 += __shfl_xor(r3, m);
    }
    if ((tid & 63) < 16) {
      const int w = tid >> 6;
      const int base = (w * 16 + (tid & 15)) * 4;
      partbuf[base + 0] = r0; partbuf[base + 1] = r1;
      partbuf[base + 2] = r2; partbuf[base + 3] = r3;
    }
    __syncthreads();
    if (tid < 64) {
      const int j2 = tid & 15, g = tid >> 4;
      float v = bias;
#pragma unroll
      for (int w = 0; w < 4; ++w) v += partbuf[(w * 16 + j2) * 4 + g];
      gl[g * 16 + j2] = v;
    }
    __syncthreads();
    if (tid < 16 && (wg * 16 + tid) < INP) {
      const int ix = wg * 16 + tid;
      const float gi = gl[tid], gf = gl[16 + tid], gg = gl[32 + tid], go = gl[48 + tid];
      const float cN = sigf(gf) * c_s[tid] + sigf(gi) * tanhf(gg);
      c_s[tid] = cN;
      out[(size_t)(SEQ - 1 - t) * INP + ix] = cN;
      const float hrN = sigf(go) * tanhf(cN);
      __hip_atomic_store(hraw + (size_t)((t + 1) & 1) * 512 + ix, hrN,
                         __ATOMIC_RELAXED, __HIP_MEMORY_SCOPE_AGENT);
    }
    if (t < SEQ - 1) {
      __syncthreads();
      if (tid == 0) {
        __threadfence();
        __hip_atomic_fetch_add(cnt, 1u, __ATOMIC_RELAXED, __HIP_MEMORY_SCOPE_AGENT);
        const unsigned target = (unsigned)NWG_D * (unsigned)(t + 1);
        while (__hip_atomic_load(cnt, __ATOMIC_RELAXED, __HIP_MEMORY_SCOPE_AGENT) < target)
          __builtin_amdgcn_s_sleep(1);
        __threadfence();
      }
      __syncthreads();
    }
  }
}

// ---------------- row softmax in-place on d_out (4096 x 457) ----------------
__global__ __launch_bounds__(512) void softmax_kernel(float* __restrict__ out) {
  const int row = blockIdx.x;
  const int tid = threadIdx.x;
  __shared__ float red[512];
  float* rp = out + (size_t)row * INP;
  float v = (tid < INP) ? rp[tid] : -INFINITY;
  red[tid] = v;
  __syncthreads();
#pragma unroll
  for (int off = 256; off > 0; off >>= 1) {
    if (tid < off) red[tid] = fmaxf(red[tid], red[tid + off]);
    __syncthreads();
  }
  const float m = red[0];
  __syncthreads();
  const float e = (tid < INP) ? expf(v - m) : 0.0f;
  red[tid] = e;
  __syncthreads();
#pragma unroll
  for (int off = 256; off > 0; off >>= 1) {
    if (tid < off) red[tid] = red[tid] + red[tid + off];
    __syncthreads();
  }
  const float s = red[0];
  if (tid < INP) rp[tid] = e / s;
}

extern "C" void kernel_launch(void* const* d_in, const int* in_sizes, int n_in,
                              void* d_out, int out_size, void* d_ws, size_t ws_size,
                              hipStream_t stream) {
  const float* x    = (const float*)d_in[0];
  const float* eWih = (const float*)d_in[1];
  const float* eWhh = (const float*)d_in[2];
  const float* ebih = (const float*)d_in[3];
  const float* ebhh = (const float*)d_in[4];
  const float* dWih = (const float*)d_in[5];
  const float* dWhh = (const float*)d_in[6];
  const float* dbih = (const float*)d_in[7];
  const float* dbhh = (const float*)d_in[8];
  const float* dWhr = (const float*)d_in[9];
  float* out = (float*)d_out;
  char* ws = (char*)d_ws;

  // ws layout:
  // [0,1024):     encoder arrival lines arr[8] (128B apart)
  // [1024,1088):  decoder barrier counter
  // [4096,20480): hbuf 2x2048 f32 (double-buffered h)
  // [20480,24576): hraw 2x512 f32
  // [24576,57344): bsum
  // [57344,65536): btot
  // [65536, +3.5MB): Wfold 1828x480
  unsigned* arr_e = (unsigned*)(ws + 0);
  unsigned* cnt_d = (unsigned*)(ws + 1024);
  float* hbuf  = (float*)(ws + 4096);
  float* hraw  = (float*)(ws + 4096 + 16384);
  float* bsum  = (float*)(ws + 24576);
  float* btot  = (float*)(ws + 24576 + 32768);
  float* Wfold = (float*)(ws + 65536);

  hipMemsetAsync(ws, 0, 24576, stream);  // counters + hbuf + hraw
  bias_kernel<<<40, 256, 0, stream>>>(ebih, ebhh, dbih, dbhh, bsum, btot);
  fold_gemm<<<dim3(8, 29), 256, 0, stream>>>(dWih, dWhh, dWhr, Wfold);
  enc_kernel<<<NWG_E, 256, 0, stream>>>(x, eWih, eWhh, bsum, hbuf, arr_e);
  dec_kernel<<<NWG_D, 256, 0, stream>>>(dWih, Wfold, btot, hbuf, hraw, out, cnt_d);
  softmax_kernel<<<SEQ, 512, 0, stream>>>(out);
}

// Round 3
// 50553.903 us; speedup vs baseline: 2.5562x; 1.5290x over previous
//
#include <hip/hip_runtime.h>
#include <cmath>

#define SEQ 4096
#define INP 457
#define EMB 2048
#define NWG_E 256   // encoder: 1 WG (512 thr) per CU, weights register-resident under a 256-VGPR budget
#define NWG_D 29    // decoder: 29 WGs x 16 c-indices = 464 >= 457

typedef unsigned long long u64t;

__device__ __forceinline__ float sigf(float v) { return 1.0f / (1.0f + expf(-v)); }

// ---------------- bias precompute ----------------
__global__ void bias_kernel(const float* __restrict__ ebih, const float* __restrict__ ebhh,
                            const float* __restrict__ dbih, const float* __restrict__ dbhh,
                            float* __restrict__ bsum, float* __restrict__ btot) {
  int i = blockIdx.x * 256 + threadIdx.x;
  if (i < 4 * EMB) bsum[i] = ebih[i] + ebhh[i];
  if (i < 4 * INP) btot[i] = dbih[i] + dbhh[i];
}

// ---------------- Wfold = (dec_Wih + dec_Whh) @ dec_Whr  (1828 x 480, pad cols zero) ----------------
__global__ __launch_bounds__(256) void fold_gemm(const float* __restrict__ dWih,
                                                 const float* __restrict__ dWhh,
                                                 const float* __restrict__ dWhr,
                                                 float* __restrict__ C) {
  const int bx = blockIdx.x, by = blockIdx.y;
  const int tid = threadIdx.x;
  const int tx = tid & 15, ty = tid >> 4;
  __shared__ float As[16][65];
  __shared__ float Bs[16][65];
  float acc[4][4] = {};
  for (int k0 = 0; k0 < EMB; k0 += 16) {
#pragma unroll
    for (int e = 0; e < 4; ++e) {
      int eid = tid * 4 + e;
      int m = eid >> 4, k = eid & 15;
      int row = by * 64 + m;
      float v = 0.0f;
      if (row < 4 * INP) {
        size_t a = (size_t)row * EMB + k0 + k;
        v = dWih[a] + dWhh[a];
      }
      As[k][m] = v;
    }
#pragma unroll
    for (int e = 0; e < 4; ++e) {
      int eid = tid * 4 + e;
      int k = eid >> 6, c = eid & 63;
      int col = bx * 64 + c;
      Bs[k][c] = (col < INP) ? dWhr[(size_t)(k0 + k) * INP + col] : 0.0f;
    }
    __syncthreads();
#pragma unroll
    for (int k = 0; k < 16; ++k) {
      float a0 = As[k][ty * 4 + 0], a1 = As[k][ty * 4 + 1], a2 = As[k][ty * 4 + 2], a3 = As[k][ty * 4 + 3];
      float b0 = Bs[k][tx * 4 + 0], b1 = Bs[k][tx * 4 + 1], b2 = Bs[k][tx * 4 + 2], b3 = Bs[k][tx * 4 + 3];
      acc[0][0] += a0 * b0; acc[0][1] += a0 * b1; acc[0][2] += a0 * b2; acc[0][3] += a0 * b3;
      acc[1][0] += a1 * b0; acc[1][1] += a1 * b1; acc[1][2] += a1 * b2; acc[1][3] += a1 * b3;
      acc[2][0] += a2 * b0; acc[2][1] += a2 * b1; acc[2][2] += a2 * b2; acc[2][3] += a2 * b3;
      acc[3][0] += a3 * b0; acc[3][1] += a3 * b1; acc[3][2] += a3 * b2; acc[3][3] += a3 * b3;
    }
    __syncthreads();
  }
#pragma unroll
  for (int i = 0; i < 4; ++i) {
    int row = by * 64 + ty * 4 + i;
    if (row >= 4 * INP) continue;
#pragma unroll
    for (int j = 0; j < 4; ++j) {
      int col = bx * 64 + tx * 4 + j;
      if (col < 480) C[(size_t)row * 480 + col] = acc[i][j];
    }
  }
}

// ---------------- persistent encoder ----------------
// 256 WGs x 512 thr (8 waves = 2/SIMD, 256-VGPR budget -> no spill).
// WG w owns h-indices [w*8, w*8+8). Thread: j = tid&7, kc = tid>>3 (64 k-chunks of 32).
// Regs: Whh 4 gates x 8 float4 = 128; Wih 4 x 2 float4 = 32; acc 16; ~200 total.
// Barrier: per-WG epoch STORE (no RMW) + wave0 coalesced poll of all 256 epochs.
// h granules XOR-swizzled in LDS -> conflict-free ds_read_b128.
__global__ __launch_bounds__(512, 2) void enc_kernel(
    const float* __restrict__ x, const float* __restrict__ Wih,
    const float* __restrict__ Whh, const float* __restrict__ bsum,
    float* __restrict__ hbuf, unsigned* __restrict__ ep) {
  const int tid = threadIdx.x;
  const int wg  = blockIdx.x;
  const int j   = tid & 7;
  const int kc  = tid >> 3;            // 0..63
  const int jbase = wg * 8;

  float4 whh4[4][8];
  float4 wih4[4][2];
#pragma unroll
  for (int g = 0; g < 4; ++g) {
    const size_t row = (size_t)(g * EMB + jbase + j);
    const float* wp = Whh + row * EMB + kc * 32;
#pragma unroll
    for (int q = 0; q < 8; ++q) whh4[g][q] = *(const float4*)(wp + 4 * q);
    const float* ip = Wih + row * INP;
    float tmp[8];
#pragma unroll
    for (int i = 0; i < 8; ++i) {
      const int c = kc * 8 + i;
      tmp[i] = (c < INP) ? ip[c] : 0.0f;
    }
    wih4[g][0] = make_float4(tmp[0], tmp[1], tmp[2], tmp[3]);
    wih4[g][1] = make_float4(tmp[4], tmp[5], tmp[6], tmp[7]);
  }

  __shared__ float4 hlds4[512];        // 8 KB: h as swizzled 16B granules
  __shared__ float4 xl4[128];          // x row (512 floats, pad 0)
  __shared__ float  partbuf[256];      // [wave][j][gate]
  __shared__ float  b_s[32];
  __shared__ float  c_s[8];
  if (tid < 32) b_s[tid] = bsum[(tid >> 3) * EMB + jbase + (tid & 7)];
  if (tid < 8)  c_s[tid] = 0.0f;
  const int sw = kc & 7;
  const int hphys = tid ^ ((tid >> 3) & 7);   // granule swizzle (bijection per 8-block)

  for (int t = 0; t < SEQ; ++t) {
    // ---- wait until all WGs posted h_t (epoch >= t); wave 0 polls, read-only ----
    if (t > 0 && tid < 64) {
      const unsigned target = (unsigned)t;
      const unsigned* e4 = ep + tid * 4;
      for (;;) {
        const unsigned e0 = __hip_atomic_load(e4 + 0, __ATOMIC_RELAXED, __HIP_MEMORY_SCOPE_AGENT);
        const unsigned e1 = __hip_atomic_load(e4 + 1, __ATOMIC_RELAXED, __HIP_MEMORY_SCOPE_AGENT);
        const unsigned e2 = __hip_atomic_load(e4 + 2, __ATOMIC_RELAXED, __HIP_MEMORY_SCOPE_AGENT);
        const unsigned e3 = __hip_atomic_load(e4 + 3, __ATOMIC_RELAXED, __HIP_MEMORY_SCOPE_AGENT);
        unsigned mn = e0 < e1 ? e0 : e1;
        const unsigned m2 = e2 < e3 ? e2 : e3;
        mn = mn < m2 ? mn : m2;
        if (__all(mn >= target)) break;
        __builtin_amdgcn_s_sleep(1);
      }
    }
    __syncthreads();

    // ---- stage h_t (agent atomics -> LLC) and x_t into LDS ----
    {
      const u64t* hs = (const u64t*)(hbuf + (size_t)(t & 1) * EMB) + tid * 2;
      const u64t u0 = __hip_atomic_load(hs + 0, __ATOMIC_RELAXED, __HIP_MEMORY_SCOPE_AGENT);
      const u64t u1 = __hip_atomic_load(hs + 1, __ATOMIC_RELAXED, __HIP_MEMORY_SCOPE_AGENT);
      const float2 f0 = __builtin_bit_cast(float2, u0);
      const float2 f1 = __builtin_bit_cast(float2, u1);
      hlds4[hphys] = make_float4(f0.x, f0.y, f1.x, f1.y);
      float xv = 0.0f;
      if (tid < INP) xv = x[(size_t)t * INP + tid];
      ((float*)xl4)[tid] = xv;
    }
    __syncthreads();

    // ---- MAC: 4 gates x (8 x-floats + 32 h-floats) ----
    float4 a0 = make_float4(0, 0, 0, 0), a1 = a0, a2 = a0, a3 = a0;
#pragma unroll
    for (int q = 0; q < 2; ++q) {
      const float4 hv = xl4[kc * 2 + q];
      a0.x += wih4[0][q].x * hv.x; a0.y += wih4[0][q].y * hv.y; a0.z += wih4[0][q].z * hv.z; a0.w += wih4[0][q].w * hv.w;
      a1.x += wih4[1][q].x * hv.x; a1.y += wih4[1][q].y * hv.y; a1.z += wih4[1][q].z * hv.z; a1.w += wih4[1][q].w * hv.w;
      a2.x += wih4[2][q].x * hv.x; a2.y += wih4[2][q].y * hv.y; a2.z += wih4[2][q].z * hv.z; a2.w += wih4[2][q].w * hv.w;
      a3.x += wih4[3][q].x * hv.x; a3.y += wih4[3][q].y * hv.y; a3.z += wih4[3][q].z * hv.z; a3.w += wih4[3][q].w * hv.w;
    }
#pragma unroll
    for (int q = 0; q < 8; ++q) {
      const float4 hv = hlds4[kc * 8 + (q ^ sw)];
      a0.x += whh4[0][q].x * hv.x; a0.y += whh4[0][q].y * hv.y; a0.z += whh4[0][q].z * hv.z; a0.w += whh4[0][q].w * hv.w;
      a1.x += whh4[1][q].x * hv.x; a1.y += whh4[1][q].y * hv.y; a1.z += whh4[1][q].z * hv.z; a1.w += whh4[1][q].w * hv.w;
      a2.x += whh4[2][q].x * hv.x; a2.y += whh4[2][q].y * hv.y; a2.z += whh4[2][q].z * hv.z; a2.w += whh4[2][q].w * hv.w;
      a3.x += whh4[3][q].x * hv.x; a3.y += whh4[3][q].y * hv.y; a3.z += whh4[3][q].z * hv.z; a3.w += whh4[3][q].w * hv.w;
    }

    // ---- reduce across kc: in-wave butterfly (lane bits 3,4,5) then cross-wave via LDS ----
    float r0 = (a0.x + a0.y) + (a0.z + a0.w);
    float r1 = (a1.x + a1.y) + (a1.z + a1.w);
    float r2 = (a2.x + a2.y) + (a2.z + a2.w);
    float r3 = (a3.x + a3.y) + (a3.z + a3.w);
#pragma unroll
    for (int m = 8; m < 64; m <<= 1) {
      r0 += __shfl_xor(r0, m); r1 += __shfl_xor(r1, m);
      r2 += __shfl_xor(r2, m); r3 += __shfl_xor(r3, m);
    }
    if ((tid & 63) < 8) {
      float* pb = partbuf + (tid >> 6) * 32 + j * 4;
      pb[0] = r0; pb[1] = r1; pb[2] = r2; pb[3] = r3;
    }
    __syncthreads();

    // ---- activation + h_{t+1} store (tid<8) ----
    if (tid < 8) {
      float s0 = 0.f, s1 = 0.f, s2 = 0.f, s3 = 0.f;
#pragma unroll
      for (int w = 0; w < 8; ++w) {
        const float* pb = partbuf + w * 32 + tid * 4;
        s0 += pb[0]; s1 += pb[1]; s2 += pb[2]; s3 += pb[3];
      }
      const float gi = s0 + b_s[tid], gf = s1 + b_s[8 + tid];
      const float gg = s2 + b_s[16 + tid], go = s3 + b_s[24 + tid];
      const float cN = sigf(gf) * c_s[tid] + sigf(gi) * tanhf(gg);
      c_s[tid] = cN;
      const float hN = sigf(go) * tanhf(cN);
      __hip_atomic_store(hbuf + (size_t)((t + 1) & 1) * EMB + jbase + tid, hN,
                         __ATOMIC_RELAXED, __HIP_MEMORY_SCOPE_AGENT);
      __threadfence();   // h stores globally visible before epoch post
    }
    __syncthreads();
    if (tid == 0)
      __hip_atomic_store(ep + wg, (unsigned)(t + 1), __ATOMIC_RELAXED, __HIP_MEMORY_SCOPE_AGENT);
  }
}

// ---------------- persistent decoder ----------------
// 29 WGs x 256 thr. jj = tid&15 (c-idx), kc = tid>>4. Wfold 4x15 float2 = 120 regs.
// Same epoch-store barrier (29 slots).
__global__ __launch_bounds__(256, 1) void dec_kernel(
    const float* __restrict__ dWih, const float* __restrict__ Wfold,
    const float* __restrict__ btot, const float* __restrict__ henc,
    float* __restrict__ hraw, float* __restrict__ out, unsigned* __restrict__ ep) {
  const int tid = threadIdx.x;
  const int wg  = blockIdx.x;
  const int jj  = tid & 15;
  const int kc  = tid >> 4;          // 0..15
  const int idx = wg * 16 + jj;
  const bool valid = (idx < INP);
  const int id0 = valid ? idx : 0;

  float2 wd2[4][15];
#pragma unroll
  for (int g = 0; g < 4; ++g) {
    const float* wp = Wfold + (size_t)(g * INP + id0) * 480 + kc * 30;
#pragma unroll
    for (int q = 0; q < 15; ++q)
      wd2[g][q] = valid ? *(const float2*)(wp + 2 * q) : make_float2(0.0f, 0.0f);
  }

  __shared__ float2 dl2[256];
  __shared__ float  partbuf[256];
  __shared__ float  b_s[64];
  __shared__ float  c_s[16];
  if (tid < 64) {
    const int ix = wg * 16 + (tid & 15);
    b_s[tid] = (ix < INP) ? btot[(tid >> 4) * INP + ix] : 0.0f;
  }
  if (tid < 16) c_s[tid] = 0.0f;

  for (int t = 0; t < SEQ; ++t) {
    if (t > 0 && tid < 64) {
      const unsigned target = (unsigned)t;
      const unsigned* e1 = ep + (tid < 29 ? tid : 28);
      for (;;) {
        const unsigned e = __hip_atomic_load(e1, __ATOMIC_RELAXED, __HIP_MEMORY_SCOPE_AGENT);
        if (__all(e >= target)) break;
        __builtin_amdgcn_s_sleep(1);
      }
    }
    __syncthreads();
    if (t > 0 && tid < 240) {
      const u64t u = __hip_atomic_load((const u64t*)(hraw + (size_t)(t & 1) * 512) + tid,
                                       __ATOMIC_RELAXED, __HIP_MEMORY_SCOPE_AGENT);
      dl2[tid] = __builtin_bit_cast(float2, u);
    }
    __syncthreads();

    float2 acc0 = make_float2(0, 0), acc1 = acc0, acc2 = acc0, acc3 = acc0;
    if (t == 0) {
      if (valid) {
#pragma unroll 4
        for (int q = 0; q < 32; ++q) {
          const float4 hv = *(const float4*)(henc + kc * 128 + 4 * q);
          const float4 w0 = *(const float4*)(dWih + (size_t)(0 * INP + idx) * EMB + kc * 128 + 4 * q);
          const float4 w1 = *(const float4*)(dWih + (size_t)(1 * INP + idx) * EMB + kc * 128 + 4 * q);
          const float4 w2 = *(const float4*)(dWih + (size_t)(2 * INP + idx) * EMB + kc * 128 + 4 * q);
          const float4 w3 = *(const float4*)(dWih + (size_t)(3 * INP + idx) * EMB + kc * 128 + 4 * q);
          acc0.x += w0.x * hv.x + w0.z * hv.z; acc0.y += w0.y * hv.y + w0.w * hv.w;
          acc1.x += w1.x * hv.x + w1.z * hv.z; acc1.y += w1.y * hv.y + w1.w * hv.w;
          acc2.x += w2.x * hv.x + w2.z * hv.z; acc2.y += w2.y * hv.y + w2.w * hv.w;
          acc3.x += w3.x * hv.x + w3.z * hv.z; acc3.y += w3.y * hv.y + w3.w * hv.w;
        }
      }
    } else {
#pragma unroll
      for (int q = 0; q < 15; ++q) {
        const float2 hv = dl2[kc * 15 + q];
        acc0.x += wd2[0][q].x * hv.x; acc0.y += wd2[0][q].y * hv.y;
        acc1.x += wd2[1][q].x * hv.x; acc1.y += wd2[1][q].y * hv.y;
        acc2.x += wd2[2][q].x * hv.x; acc2.y += wd2[2][q].y * hv.y;
        acc3.x += wd2[3][q].x * hv.x; acc3.y += wd2[3][q].y * hv.y;
      }
    }
    float r0 = acc0.x + acc0.y, r1 = acc1.x + acc1.y, r2 = acc2.x + acc2.y, r3 = acc3.x + acc3.y;
#pragma unroll
    for (int m = 16; m < 64; m <<= 1) {
      r0 += __shfl_xor(r0, m); r1 += __shfl_xor(r1, m);
      r2 += __shfl_xor(r2, m); r3 += __shfl_xor(r3, m);
    }
    if ((tid & 63) < 16) {
      float* pb = partbuf + (tid >> 6) * 64 + (tid & 15) * 4;
      pb[0] = r0; pb[1] = r1; pb[2] = r2; pb[3] = r3;
    }
    __syncthreads();
    if (tid < 16) {
      float s0 = 0.f, s1 = 0.f, s2 = 0.f, s3 = 0.f;
#pragma unroll
      for (int w = 0; w < 4; ++w) {
        const float* pb = partbuf + w * 64 + tid * 4;
        s0 += pb[0]; s1 += pb[1]; s2 += pb[2]; s3 += pb[3];
      }
      const float gi = s0 + b_s[tid], gf = s1 + b_s[16 + tid];
      const float gg = s2 + b_s[32 + tid], go = s3 + b_s[48 + tid];
      const float cN = sigf(gf) * c_s[tid] + sigf(gi) * tanhf(gg);
      c_s[tid] = cN;
      const int ix = wg * 16 + tid;
      if (ix < INP) {
        out[(size_t)(SEQ - 1 - t) * INP + ix] = cN;
        const float hrN = sigf(go) * tanhf(cN);
        __hip_atomic_store(hraw + (size_t)((t + 1) & 1) * 512 + ix, hrN,
                           __ATOMIC_RELAXED, __HIP_MEMORY_SCOPE_AGENT);
      }
      __threadfence();
    }
    __syncthreads();
    if (tid == 0)
      __hip_atomic_store(ep + wg, (unsigned)(t + 1), __ATOMIC_RELAXED, __HIP_MEMORY_SCOPE_AGENT);
  }
}

// ---------------- row softmax in-place on d_out (4096 x 457) ----------------
__global__ __launch_bounds__(512) void softmax_kernel(float* __restrict__ out) {
  const int row = blockIdx.x;
  const int tid = threadIdx.x;
  __shared__ float red[512];
  float* rp = out + (size_t)row * INP;
  float v = (tid < INP) ? rp[tid] : -INFINITY;
  red[tid] = v;
  __syncthreads();
#pragma unroll
  for (int off = 256; off > 0; off >>= 1) {
    if (tid < off) red[tid] = fmaxf(red[tid], red[tid + off]);
    __syncthreads();
  }
  const float m = red[0];
  __syncthreads();
  const float e = (tid < INP) ? expf(v - m) : 0.0f;
  red[tid] = e;
  __syncthreads();
#pragma unroll
  for (int off = 256; off > 0; off >>= 1) {
    if (tid < off) red[tid] = red[tid] + red[tid + off];
    __syncthreads();
  }
  const float s = red[0];
  if (tid < INP) rp[tid] = e / s;
}

extern "C" void kernel_launch(void* const* d_in, const int* in_sizes, int n_in,
                              void* d_out, int out_size, void* d_ws, size_t ws_size,
                              hipStream_t stream) {
  const float* x    = (const float*)d_in[0];
  const float* eWih = (const float*)d_in[1];
  const float* eWhh = (const float*)d_in[2];
  const float* ebih = (const float*)d_in[3];
  const float* ebhh = (const float*)d_in[4];
  const float* dWih = (const float*)d_in[5];
  const float* dWhh = (const float*)d_in[6];
  const float* dbih = (const float*)d_in[7];
  const float* dbhh = (const float*)d_in[8];
  const float* dWhr = (const float*)d_in[9];
  float* out = (float*)d_out;
  char* ws = (char*)d_ws;

  // ws layout:
  // [0,1024):        enc epochs ep[256]
  // [1024,1152):     dec epochs ep[29]
  // [4096,20480):    hbuf 2x2048 f32 (double-buffered h; buf0 = h0 = 0)
  // [20480,24576):   hraw 2x512 f32
  // [24576,57344):   bsum
  // [57344,65536):   btot
  // [65536,+3.5MB):  Wfold 1828x480
  unsigned* ep_e = (unsigned*)(ws + 0);
  unsigned* ep_d = (unsigned*)(ws + 1024);
  float* hbuf  = (float*)(ws + 4096);
  float* hraw  = (float*)(ws + 4096 + 16384);
  float* bsum  = (float*)(ws + 24576);
  float* btot  = (float*)(ws + 24576 + 32768);
  float* Wfold = (float*)(ws + 65536);

  hipMemsetAsync(ws, 0, 24576, stream);  // epochs + hbuf + hraw
  bias_kernel<<<40, 256, 0, stream>>>(ebih, ebhh, dbih, dbhh, bsum, btot);
  fold_gemm<<<dim3(8, 29), 256, 0, stream>>>(dWih, dWhh, dWhr, Wfold);
  enc_kernel<<<NWG_E, 512, 0, stream>>>(x, eWih, eWhh, bsum, hbuf, ep_e);
  dec_kernel<<<NWG_D, 256, 0, stream>>>(dWih, Wfold, btot, hbuf, hraw, out, ep_d);
  softmax_kernel<<<SEQ, 512, 0, stream>>>(out);
}